// Round 8
// baseline (2416.959 us; speedup 1.0000x reference)
//
#include <hip/hip_runtime.h>
#include <hip/hip_bf16.h>

// NormalAttention: B=4, N=1600, C=512, heads=8, dh=64. out = softmax(qk^T/8)@k.
// R8 = R7 (LDS-free attn, fragment-ordered k2/kt2) +
//   (1) q pre-scaled by 0.125*log2(e); attn uses exp2f (native v_exp_f32)
//   (2) register double-buffer of the S^T A-frags (kf) across K-iterations
//   (3) attn __launch_bounds__(256,4) caps VGPR at 128

typedef __hip_bfloat16 bf16;
typedef __attribute__((ext_vector_type(8))) short short8;
typedef __attribute__((ext_vector_type(4))) short bfx4;
typedef __attribute__((ext_vector_type(4))) float f32x4;

#define NSP 1600
#define CDIM 512
#define DH 64

__device__ __forceinline__ f32x4 mfma32(short8 a, short8 b, f32x4 c) {
  return __builtin_amdgcn_mfma_f32_16x16x32_bf16(a, b, c, 0, 0, 0);
}

#if __has_builtin(__builtin_amdgcn_mfma_f32_16x16x16bf16_1k)
__device__ __forceinline__ f32x4 mfma_k16(bfx4 a, bfx4 b, f32x4 c) {
  return __builtin_amdgcn_mfma_f32_16x16x16bf16_1k(a, b, c, 0, 0, 0);
}
#else
__device__ __forceinline__ f32x4 mfma_k16(bfx4 a, bfx4 b, f32x4 c) {
  short8 a8 = {a.x, a.y, a.z, a.w, 0, 0, 0, 0};
  short8 b8 = {b.x, b.y, b.z, b.w, 0, 0, 0, 0};
  return __builtin_amdgcn_mfma_f32_16x16x32_bf16(a8, b8, c, 0, 0, 0);
}
#endif

__device__ __forceinline__ short8 cvt8(float4 v0, float4 v1) {
  short8 r; bf16* p = (bf16*)&r;
  p[0] = __float2bfloat16(v0.x); p[1] = __float2bfloat16(v0.y);
  p[2] = __float2bfloat16(v0.z); p[3] = __float2bfloat16(v0.w);
  p[4] = __float2bfloat16(v1.x); p[5] = __float2bfloat16(v1.y);
  p[6] = __float2bfloat16(v1.z); p[7] = __float2bfloat16(v1.w);
  return r;
}

// ---------------------------------------------------------------------------
// cvt: x,w -> bf16 (plain); sin/cos -> (d,n) fp32 transpose.  (R5 verbatim)
// ---------------------------------------------------------------------------
extern "C" __global__ __launch_bounds__(256)
void cvt_kernel(const float* __restrict__ x, const float* __restrict__ w,
                const float* __restrict__ sin_t, const float* __restrict__ cos_t,
                bf16* __restrict__ x_bf, bf16* __restrict__ w_bf,
                float* __restrict__ sinT, float* __restrict__ cosT)
{
  __shared__ float t_lds[64][68];
  const int bid = blockIdx.x, tid = threadIdx.x;
  if (bid < 1600) {
    const size_t i = (size_t)bid * 2048 + tid * 8;
    float4 v0 = *(const float4*)(x + i);
    float4 v1 = *(const float4*)(x + i + 4);
    *(short8*)(x_bf + i) = cvt8(v0, v1);
  } else if (bid < 1856) {
    const size_t i = (size_t)(bid - 1600) * 2048 + tid * 8;
    float4 v0 = *(const float4*)(w + i);
    float4 v1 = *(const float4*)(w + i + 4);
    *(short8*)(w_bf + i) = cvt8(v0, v1);
  } else {
    const int t = bid - 1856;
    const float* src = (t < 25) ? sin_t : cos_t;
    float* dst = (t < 25) ? sinT : cosT;
    const int nt = (t < 25) ? t : t - 25;
    const int r = tid >> 2, c = (tid & 3) * 16;
#pragma unroll
    for (int j = 0; j < 4; ++j)
      *(float4*)&t_lds[r][c + j * 4] =
          *(const float4*)(src + (size_t)(nt * 64 + r) * 64 + c + j * 4);
    __syncthreads();
#pragma unroll
    for (int j4 = 0; j4 < 4; ++j4) {
      float4 o;
      o.x = t_lds[c + j4 * 4 + 0][r];
      o.y = t_lds[c + j4 * 4 + 1][r];
      o.z = t_lds[c + j4 * 4 + 2][r];
      o.w = t_lds[c + j4 * 4 + 3][r];
      *(float4*)(dst + (size_t)r * NSP + nt * 64 + c + j4 * 4) = o;
    }
  }
}

// ---------------------------------------------------------------------------
// proj: 128x128 tile, BK=64 (R5-proven main loop). q scaled by 0.125*log2(e)
// so attn can use exp2. k epilogue writes fragment-ordered k2_ws / kt2_ws.
// ---------------------------------------------------------------------------
extern "C" __global__ __launch_bounds__(256)
void proj_kernel(const bf16* __restrict__ x_bf, const bf16* __restrict__ w_bf,
                 const float* __restrict__ bias, const float* __restrict__ sinT,
                 const float* __restrict__ cosT, bf16* __restrict__ q_ws,
                 bf16* __restrict__ k2_ws, bf16* __restrict__ kt2_ws)
{
  __shared__ __align__(16) char smem[36864];
  bf16 (*x_lds)[72] = (bf16(*)[72])smem;              // [128][72]
  bf16 (*w_lds)[72] = (bf16(*)[72])(smem + 18432);    // [128][72]
  bf16* ep = (bf16*)smem;                             // [128][132] overlay

  const int tid  = threadIdx.x;
  const int wave = tid >> 6;
  const int lane = tid & 63;
  const int col  = lane & 15;
  const int quad = lane >> 4;
  const int wm = wave >> 1, wo = wave & 1;
  const int m0 = blockIdx.x * 128;
  const int o0 = blockIdx.y * 128;

  f32x4 acc[4][4];
#pragma unroll
  for (int i = 0; i < 4; ++i)
#pragma unroll
    for (int j = 0; j < 4; ++j) acc[i][j] = {0.f, 0.f, 0.f, 0.f};

  const int srow = tid >> 1;
  const int sch  = (tid & 1) * 32;

  for (int kt = 0; kt < 8; ++kt) {
    __syncthreads();
    {
      const bf16* xs = x_bf + (size_t)(m0 + srow) * CDIM + kt * 64 + sch;
      const bf16* ws = w_bf + (size_t)(o0 + srow) * CDIM + kt * 64 + sch;
#pragma unroll
      for (int j = 0; j < 4; ++j) {
        *(short8*)&x_lds[srow][sch + j * 8] = *(const short8*)(xs + j * 8);
        *(short8*)&w_lds[srow][sch + j * 8] = *(const short8*)(ws + j * 8);
      }
    }
    __syncthreads();
#pragma unroll
    for (int half = 0; half < 2; ++half) {
      short8 af[4], bfr[4];
#pragma unroll
      for (int mt = 0; mt < 4; ++mt)
        af[mt] = *(short8*)&x_lds[wm * 64 + mt * 16 + col][half * 32 + quad * 8];
#pragma unroll
      for (int ot = 0; ot < 4; ++ot)
        bfr[ot] = *(short8*)&w_lds[wo * 64 + ot * 16 + col][half * 32 + quad * 8];
#pragma unroll
      for (int mt = 0; mt < 4; ++mt)
#pragma unroll
        for (int ot = 0; ot < 4; ++ot)
          acc[mt][ot] = mfma32(af[mt], bfr[ot], acc[mt][ot]);
    }
  }

  // ---- epilogue stage 1: theta_shift -> ep[o_local][m_local] (bf16) ----
  __syncthreads();
  const int b_idx = (m0 + wm * 64) / NSP;
  const int n0w   = m0 + wm * 64 - b_idx * NSP;
  const bool isq  = (o0 < 512);
#pragma unroll
  for (int ot = 0; ot < 4; ++ot) {
    const int o_local = wo * 64 + ot * 16 + col;
    const int o_g = o0 + o_local;
    const float bv = bias[o_g];
    const int d = o_g & 63;
#pragma unroll
    for (int mt = 0; mt < 4; ++mt) {
      const int nl = mt * 16 + quad * 4;
      float t[4], rot[4];
#pragma unroll
      for (int r = 0; r < 4; ++r) t[r] = acc[mt][ot][r] + bv;
#pragma unroll
      for (int r = 0; r < 4; ++r) {
        float tp = __shfl_xor(t[r], 1, 64);
        rot[r] = (lane & 1) ? tp : -tp;
      }
      const float4 c4 = *(const float4*)(cosT + (size_t)d * NSP + n0w + nl);
      const float4 s4 = *(const float4*)(sinT + (size_t)d * NSP + n0w + nl);
      float res[4];
      res[0] = t[0] * c4.x + rot[0] * s4.x;
      res[1] = t[1] * c4.y + rot[1] * s4.y;
      res[2] = t[2] * c4.z + rot[2] * s4.z;
      res[3] = t[3] * c4.w + rot[3] * s4.w;
      if (isq) {
#pragma unroll
        for (int r = 0; r < 4; ++r) res[r] *= 0.1803368801111204f;  // 0.125*log2(e)
      }
      bfx4 pk; bf16* pp = (bf16*)&pk;
#pragma unroll
      for (int r = 0; r < 4; ++r) pp[r] = __float2bfloat16(res[r]);
      *(bfx4*)&ep[o_local * 132 + wm * 64 + nl] = pk;
    }
  }
  __syncthreads();

  // ---- epilogue stage 2: coalesced global stores ----
  if (isq) {   // q_ws (bh,n,d) natural
    const int m_l = tid >> 1, half = tid & 1;
    const int gm = m0 + m_l;
    const int bi = gm / NSP, n = gm - bi * NSP;
    const int h = (o0 >> 6) + half;
    bf16* base = q_ws + ((size_t)(bi * 8 + h) * NSP + n) * 64;
#pragma unroll
    for (int c = 0; c < 8; ++c) {
      short8 v; bf16* vp = (bf16*)&v;
#pragma unroll
      for (int j = 0; j < 8; ++j) vp[j] = ep[(half * 64 + c * 8 + j) * 132 + m_l];
      *(short8*)(base + c * 8) = v;
    }
  } else {
    const int h0 = (o0 - 512) >> 6;
    // k2_ws: per (bh,ktile) 512 chunks [kh][ti][f][quad][col]
#pragma unroll
    for (int it = 0; it < 8; ++it) {
      const int ci = it * 256 + tid;
      const int hh = ci >> 10, T = (ci >> 9) & 1, inner = ci & 511;
      const int ccol = inner & 15, cq = (inner >> 4) & 3;
      const int f = (inner >> 6) & 1, ti = (inner >> 7) & 1, kh2 = (inner >> 8) & 1;
      const int gmb = m0 + T * 64;
      const int bi = gmb / NSP, ktile = (gmb - bi * NSP) >> 6;
      const int m_l = T * 64 + (2 * kh2 + ti) * 16 + ccol;
      const int er0 = hh * 64 + (f * 4 + cq) * 8;
      short8 v; bf16* vp = (bf16*)&v;
#pragma unroll
      for (int j = 0; j < 8; ++j) vp[j] = ep[(er0 + j) * 132 + m_l];
      *(short8*)(k2_ws +
          (((size_t)(bi * 8 + h0 + hh) * 25 + ktile) * 512 + inner) * 8) = v;
    }
    // kt2_ws: per (bh,ktile) 512 chunks [kh][dt][quad][col]
#pragma unroll
    for (int it = 0; it < 8; ++it) {
      const int ci = it * 256 + tid;
      const int hh = ci >> 10, T = (ci >> 9) & 1, inner = ci & 511;
      const int ccol = inner & 15, cq = (inner >> 4) & 3;
      const int dt = (inner >> 6) & 3, kh2 = (inner >> 8) & 1;
      const int gmb = m0 + T * 64;
      const int bi = gmb / NSP, ktile = (gmb - bi * NSP) >> 6;
      const bf16* eprow =
          ep + (hh * 64 + dt * 16 + ccol) * 132 + T * 64 + kh2 * 32 + cq * 4;
      short8 v;
      ((bfx4*)&v)[0] = *(const bfx4*)(eprow);
      ((bfx4*)&v)[1] = *(const bfx4*)(eprow + 16);
      *(short8*)(kt2_ws +
          (((size_t)(bi * 8 + h0 + hh) * 25 + ktile) * 512 + inner) * 8) = v;
    }
  }
}

// ---------------------------------------------------------------------------
// attn: LDS-free K-loop, kf register double-buffer, exp2 softmax.
// grid (25,32), 4 waves: qg=wave&1 (32 qcols), kh=wave>>1 (32 keys).
// ---------------------------------------------------------------------------
extern "C" __global__ __launch_bounds__(256, 4)
void attn_kernel(const bf16* __restrict__ q_ws, const bf16* __restrict__ k2_ws,
                 const bf16* __restrict__ kt2_ws, float* __restrict__ out)
{
  __shared__ float red[2][64][36];

  const int qt = blockIdx.x, bh = blockIdx.y;
  const int b = bh >> 3, h = bh & 7;
  const int tid  = threadIdx.x;
  const int wave = tid >> 6;
  const int lane = tid & 63;
  const int col  = lane & 15;
  const int quad = lane >> 4;
  const int qg = wave & 1, kh = wave >> 1;

  // loop-invariant Q B-fragments
  short8 qb[2][2];
#pragma unroll
  for (int ct = 0; ct < 2; ++ct) {
    const bf16* qp =
        q_ws + ((size_t)bh * NSP + qt * 64 + (qg * 2 + ct) * 16 + col) * 64;
    qb[ct][0] = *(const short8*)(qp + quad * 8);
    qb[ct][1] = *(const short8*)(qp + 32 + quad * 8);
  }

  f32x4 oacc[4][2];
#pragma unroll
  for (int i = 0; i < 4; ++i)
#pragma unroll
    for (int j = 0; j < 2; ++j) oacc[i][j] = {0.f, 0.f, 0.f, 0.f};
  float l_part[2] = {0.f, 0.f};

  const bf16* k2b  = k2_ws  + (size_t)bh * 25 * 4096;
  const bf16* kt2b = kt2_ws + (size_t)bh * 25 * 4096;

  // kf double-buffer: S^T A-frags consumed at iter head -> prefetch one ahead.
  short8 kf[2][2][2];
#define LOADKF(BUF, KT)                                                        \
  {                                                                            \
    const bf16* kc_ = k2b + (KT) * 4096;                                       \
    _Pragma("unroll")                                                          \
    for (int ti_ = 0; ti_ < 2; ++ti_)                                          \
      _Pragma("unroll")                                                        \
      for (int f_ = 0; f_ < 2; ++f_)                                           \
        kf[BUF][ti_][f_] = *(const short8*)(kc_ +                              \
            (((kh * 2 + ti_) * 2 + f_) * 64 + lane) * 8);                      \
  }

  LOADKF(0, 0)

  for (int kt = 0; kt < 25; ++kt) {
    const int cur = kt & 1;
    if (kt + 1 < 25) LOADKF(cur ^ 1, kt + 1)

    // PK A-frags for this iter (consumed after QK+exp: natural latency slack)
    const bf16* kc2 = kt2b + kt * 4096;
    short8 ktf[4];
#pragma unroll
    for (int dt = 0; dt < 4; ++dt)
      ktf[dt] = *(const short8*)(kc2 + ((kh * 4 + dt) * 64 + lane) * 8);

    // S^T = K @ Q^T (q pre-scaled by log2e/8)
    f32x4 s[2][2];
#pragma unroll
    for (int ti = 0; ti < 2; ++ti)
#pragma unroll
      for (int ct = 0; ct < 2; ++ct) {
        f32x4 t = {0.f, 0.f, 0.f, 0.f};
        t = mfma32(kf[cur][ti][0], qb[ct][0], t);
        t = mfma32(kf[cur][ti][1], qb[ct][1], t);
        s[ti][ct] = t;
      }

    // P = 2^s (== exp of unscaled logits); accumulate l; pack P^T B-frags
    bfx4 p4[2][2];
#pragma unroll
    for (int ti = 0; ti < 2; ++ti)
#pragma unroll
      for (int ct = 0; ct < 2; ++ct) {
#pragma unroll
        for (int r = 0; r < 4; ++r) s[ti][ct][r] = exp2f(s[ti][ct][r]);
        l_part[ct] += s[ti][ct][0] + s[ti][ct][1] + s[ti][ct][2] + s[ti][ct][3];
        bf16* pp = (bf16*)&p4[ti][ct];
#pragma unroll
        for (int r = 0; r < 4; ++r) pp[r] = __float2bfloat16(s[ti][ct][r]);
      }

    // O^T += K^T @ P^T over this wave's 32 keys
#pragma unroll
    for (int dt = 0; dt < 4; ++dt) {
      bfx4 alo = __builtin_shufflevector(ktf[dt], ktf[dt], 0, 1, 2, 3);
      bfx4 ahi = __builtin_shufflevector(ktf[dt], ktf[dt], 4, 5, 6, 7);
#pragma unroll
      for (int ct = 0; ct < 2; ++ct) {
        oacc[dt][ct] = mfma_k16(alo, p4[0][ct], oacc[dt][ct]);
        oacc[dt][ct] = mfma_k16(ahi, p4[1][ct], oacc[dt][ct]);
      }
    }
  }

  // reduce l over quads (this wave's 32 keys)
#pragma unroll
  for (int ct = 0; ct < 2; ++ct) {
    l_part[ct] += __shfl_xor(l_part[ct], 16, 64);
    l_part[ct] += __shfl_xor(l_part[ct], 32, 64);
  }

  // cross-wave (kh) reduce via LDS
  if (wave >= 2) {
    float* dst = &red[wave - 2][lane][0];
#pragma unroll
    for (int dt = 0; dt < 4; ++dt)
#pragma unroll
      for (int ct = 0; ct < 2; ++ct)
        *(f32x4*)(dst + (dt * 2 + ct) * 4) = oacc[dt][ct];
    dst[32] = l_part[0]; dst[33] = l_part[1];
  }
  __syncthreads();
  if (wave < 2) {
    const float* srcr = &red[wave][lane][0];
#pragma unroll
    for (int dt = 0; dt < 4; ++dt)
#pragma unroll
      for (int ct = 0; ct < 2; ++ct)
        oacc[dt][ct] += *(const f32x4*)(srcr + (dt * 2 + ct) * 4);
    const float inv0 = 1.f / (l_part[0] + srcr[32]);
    const float inv1 = 1.f / (l_part[1] + srcr[33]);
#pragma unroll
    for (int ct = 0; ct < 2; ++ct) {
      const float inv = ct ? inv1 : inv0;
      const int qrow = qt * 64 + (qg * 2 + ct) * 16 + col;
      float* ob = out + ((size_t)b * NSP + qrow) * CDIM + h * 64;
#pragma unroll
      for (int dt = 0; dt < 4; ++dt) {
        float4 v;
        v.x = oacc[dt][ct][0] * inv; v.y = oacc[dt][ct][1] * inv;
        v.z = oacc[dt][ct][2] * inv; v.w = oacc[dt][ct][3] * inv;
        *(float4*)(ob + dt * 16 + quad * 4) = v;
      }
    }
  }
}

extern "C" void kernel_launch(void* const* d_in, const int* in_sizes, int n_in,
                              void* d_out, int out_size, void* d_ws, size_t ws_size,
                              hipStream_t stream) {
  const float* x     = (const float*)d_in[0];
  const float* sin_t = (const float*)d_in[1];
  const float* cos_t = (const float*)d_in[2];
  const float* w_qkv = (const float*)d_in[3];
  const float* b_qkv = (const float*)d_in[4];
  float* out = (float*)d_out;

  const size_t QK = (size_t)32 * NSP * DH;
  bf16* q_ws   = (bf16*)d_ws;
  bf16* k2_ws  = q_ws + QK;
  bf16* kt2_ws = k2_ws + QK;
  bf16* x_bf   = kt2_ws + QK;
  bf16* w_bf   = x_bf + (size_t)6400 * CDIM;
  float* sinT  = (float*)(w_bf + (size_t)1024 * CDIM);
  float* cosT  = sinT + (size_t)DH * NSP;

  cvt_kernel<<<1906, 256, 0, stream>>>(x, w_qkv, sin_t, cos_t, x_bf, w_bf, sinT, cosT);

  dim3 gproj(50, 8);
  proj_kernel<<<gproj, 256, 0, stream>>>(x_bf, w_bf, b_qkv, sinT, cosT,
                                         q_ws, k2_ws, kt2_ws);

  dim3 gattn(25, 32);
  attn_kernel<<<gattn, 256, 0, stream>>>(q_ws, k2_ws, kt2_ws, out);
}

// Round 9
// 145.882 us; speedup vs baseline: 16.5678x; 16.5678x over previous
//
#include <hip/hip_runtime.h>
#include <hip/hip_bf16.h>

// NormalAttention: B=4, N=1600, C=512, heads=8, dh=64. out = softmax(qk^T/8)@k.
// R9 = R7 LDS-free attn + exp2-folded scale (R8) + K-loop manually unrolled
// x2 with two NAMED fragment buffers (compile-time indices -> stays in VGPRs;
// R8's kf[cur] dynamic indexing spilled to scratch: WRITE_SIZE 12.8->218MB).

typedef __hip_bfloat16 bf16;
typedef __attribute__((ext_vector_type(8))) short short8;
typedef __attribute__((ext_vector_type(4))) short bfx4;
typedef __attribute__((ext_vector_type(4))) float f32x4;

#define NSP 1600
#define CDIM 512
#define DH 64

__device__ __forceinline__ f32x4 mfma32(short8 a, short8 b, f32x4 c) {
  return __builtin_amdgcn_mfma_f32_16x16x32_bf16(a, b, c, 0, 0, 0);
}

#if __has_builtin(__builtin_amdgcn_mfma_f32_16x16x16bf16_1k)
__device__ __forceinline__ f32x4 mfma_k16(bfx4 a, bfx4 b, f32x4 c) {
  return __builtin_amdgcn_mfma_f32_16x16x16bf16_1k(a, b, c, 0, 0, 0);
}
#else
__device__ __forceinline__ f32x4 mfma_k16(bfx4 a, bfx4 b, f32x4 c) {
  short8 a8 = {a.x, a.y, a.z, a.w, 0, 0, 0, 0};
  short8 b8 = {b.x, b.y, b.z, b.w, 0, 0, 0, 0};
  return __builtin_amdgcn_mfma_f32_16x16x32_bf16(a8, b8, c, 0, 0, 0);
}
#endif

__device__ __forceinline__ short8 cvt8(float4 v0, float4 v1) {
  short8 r; bf16* p = (bf16*)&r;
  p[0] = __float2bfloat16(v0.x); p[1] = __float2bfloat16(v0.y);
  p[2] = __float2bfloat16(v0.z); p[3] = __float2bfloat16(v0.w);
  p[4] = __float2bfloat16(v1.x); p[5] = __float2bfloat16(v1.y);
  p[6] = __float2bfloat16(v1.z); p[7] = __float2bfloat16(v1.w);
  return r;
}

// ---------------------------------------------------------------------------
// cvt: x,w -> bf16 (plain); sin/cos -> (d,n) fp32 transpose.  (R5 verbatim)
// ---------------------------------------------------------------------------
extern "C" __global__ __launch_bounds__(256)
void cvt_kernel(const float* __restrict__ x, const float* __restrict__ w,
                const float* __restrict__ sin_t, const float* __restrict__ cos_t,
                bf16* __restrict__ x_bf, bf16* __restrict__ w_bf,
                float* __restrict__ sinT, float* __restrict__ cosT)
{
  __shared__ float t_lds[64][68];
  const int bid = blockIdx.x, tid = threadIdx.x;
  if (bid < 1600) {
    const size_t i = (size_t)bid * 2048 + tid * 8;
    float4 v0 = *(const float4*)(x + i);
    float4 v1 = *(const float4*)(x + i + 4);
    *(short8*)(x_bf + i) = cvt8(v0, v1);
  } else if (bid < 1856) {
    const size_t i = (size_t)(bid - 1600) * 2048 + tid * 8;
    float4 v0 = *(const float4*)(w + i);
    float4 v1 = *(const float4*)(w + i + 4);
    *(short8*)(w_bf + i) = cvt8(v0, v1);
  } else {
    const int t = bid - 1856;
    const float* src = (t < 25) ? sin_t : cos_t;
    float* dst = (t < 25) ? sinT : cosT;
    const int nt = (t < 25) ? t : t - 25;
    const int r = tid >> 2, c = (tid & 3) * 16;
#pragma unroll
    for (int j = 0; j < 4; ++j)
      *(float4*)&t_lds[r][c + j * 4] =
          *(const float4*)(src + (size_t)(nt * 64 + r) * 64 + c + j * 4);
    __syncthreads();
#pragma unroll
    for (int j4 = 0; j4 < 4; ++j4) {
      float4 o;
      o.x = t_lds[c + j4 * 4 + 0][r];
      o.y = t_lds[c + j4 * 4 + 1][r];
      o.z = t_lds[c + j4 * 4 + 2][r];
      o.w = t_lds[c + j4 * 4 + 3][r];
      *(float4*)(dst + (size_t)r * NSP + nt * 64 + c + j4 * 4) = o;
    }
  }
}

// ---------------------------------------------------------------------------
// proj: 128x128 tile, BK=64 (R5-proven). q scaled by 0.125*log2(e).
// k epilogue writes fragment-ordered k2_ws / kt2_ws.  (R8 verbatim)
// ---------------------------------------------------------------------------
extern "C" __global__ __launch_bounds__(256)
void proj_kernel(const bf16* __restrict__ x_bf, const bf16* __restrict__ w_bf,
                 const float* __restrict__ bias, const float* __restrict__ sinT,
                 const float* __restrict__ cosT, bf16* __restrict__ q_ws,
                 bf16* __restrict__ k2_ws, bf16* __restrict__ kt2_ws)
{
  __shared__ __align__(16) char smem[36864];
  bf16 (*x_lds)[72] = (bf16(*)[72])smem;              // [128][72]
  bf16 (*w_lds)[72] = (bf16(*)[72])(smem + 18432);    // [128][72]
  bf16* ep = (bf16*)smem;                             // [128][132] overlay

  const int tid  = threadIdx.x;
  const int wave = tid >> 6;
  const int lane = tid & 63;
  const int col  = lane & 15;
  const int quad = lane >> 4;
  const int wm = wave >> 1, wo = wave & 1;
  const int m0 = blockIdx.x * 128;
  const int o0 = blockIdx.y * 128;

  f32x4 acc[4][4];
#pragma unroll
  for (int i = 0; i < 4; ++i)
#pragma unroll
    for (int j = 0; j < 4; ++j) acc[i][j] = {0.f, 0.f, 0.f, 0.f};

  const int srow = tid >> 1;
  const int sch  = (tid & 1) * 32;

  for (int kt = 0; kt < 8; ++kt) {
    __syncthreads();
    {
      const bf16* xs = x_bf + (size_t)(m0 + srow) * CDIM + kt * 64 + sch;
      const bf16* ws = w_bf + (size_t)(o0 + srow) * CDIM + kt * 64 + sch;
#pragma unroll
      for (int j = 0; j < 4; ++j) {
        *(short8*)&x_lds[srow][sch + j * 8] = *(const short8*)(xs + j * 8);
        *(short8*)&w_lds[srow][sch + j * 8] = *(const short8*)(ws + j * 8);
      }
    }
    __syncthreads();
#pragma unroll
    for (int half = 0; half < 2; ++half) {
      short8 af[4], bfr[4];
#pragma unroll
      for (int mt = 0; mt < 4; ++mt)
        af[mt] = *(short8*)&x_lds[wm * 64 + mt * 16 + col][half * 32 + quad * 8];
#pragma unroll
      for (int ot = 0; ot < 4; ++ot)
        bfr[ot] = *(short8*)&w_lds[wo * 64 + ot * 16 + col][half * 32 + quad * 8];
#pragma unroll
      for (int mt = 0; mt < 4; ++mt)
#pragma unroll
        for (int ot = 0; ot < 4; ++ot)
          acc[mt][ot] = mfma32(af[mt], bfr[ot], acc[mt][ot]);
    }
  }

  // ---- epilogue stage 1: theta_shift -> ep[o_local][m_local] (bf16) ----
  __syncthreads();
  const int b_idx = (m0 + wm * 64) / NSP;
  const int n0w   = m0 + wm * 64 - b_idx * NSP;
  const bool isq  = (o0 < 512);
#pragma unroll
  for (int ot = 0; ot < 4; ++ot) {
    const int o_local = wo * 64 + ot * 16 + col;
    const int o_g = o0 + o_local;
    const float bv = bias[o_g];
    const int d = o_g & 63;
#pragma unroll
    for (int mt = 0; mt < 4; ++mt) {
      const int nl = mt * 16 + quad * 4;
      float t[4], rot[4];
#pragma unroll
      for (int r = 0; r < 4; ++r) t[r] = acc[mt][ot][r] + bv;
#pragma unroll
      for (int r = 0; r < 4; ++r) {
        float tp = __shfl_xor(t[r], 1, 64);
        rot[r] = (lane & 1) ? tp : -tp;
      }
      const float4 c4 = *(const float4*)(cosT + (size_t)d * NSP + n0w + nl);
      const float4 s4 = *(const float4*)(sinT + (size_t)d * NSP + n0w + nl);
      float res[4];
      res[0] = t[0] * c4.x + rot[0] * s4.x;
      res[1] = t[1] * c4.y + rot[1] * s4.y;
      res[2] = t[2] * c4.z + rot[2] * s4.z;
      res[3] = t[3] * c4.w + rot[3] * s4.w;
      if (isq) {
#pragma unroll
        for (int r = 0; r < 4; ++r) res[r] *= 0.1803368801111204f;  // 0.125*log2(e)
      }
      bfx4 pk; bf16* pp = (bf16*)&pk;
#pragma unroll
      for (int r = 0; r < 4; ++r) pp[r] = __float2bfloat16(res[r]);
      *(bfx4*)&ep[o_local * 132 + wm * 64 + nl] = pk;
    }
  }
  __syncthreads();

  // ---- epilogue stage 2: coalesced global stores ----
  if (isq) {   // q_ws (bh,n,d) natural
    const int m_l = tid >> 1, half = tid & 1;
    const int gm = m0 + m_l;
    const int bi = gm / NSP, n = gm - bi * NSP;
    const int h = (o0 >> 6) + half;
    bf16* base = q_ws + ((size_t)(bi * 8 + h) * NSP + n) * 64;
#pragma unroll
    for (int c = 0; c < 8; ++c) {
      short8 v; bf16* vp = (bf16*)&v;
#pragma unroll
      for (int j = 0; j < 8; ++j) vp[j] = ep[(half * 64 + c * 8 + j) * 132 + m_l];
      *(short8*)(base + c * 8) = v;
    }
  } else {
    const int h0 = (o0 - 512) >> 6;
    // k2_ws: per (bh,ktile) 512 chunks [kh][ti][f][quad][col]
#pragma unroll
    for (int it = 0; it < 8; ++it) {
      const int ci = it * 256 + tid;
      const int hh = ci >> 10, T = (ci >> 9) & 1, inner = ci & 511;
      const int ccol = inner & 15, cq = (inner >> 4) & 3;
      const int f = (inner >> 6) & 1, ti = (inner >> 7) & 1, kh2 = (inner >> 8) & 1;
      const int gmb = m0 + T * 64;
      const int bi = gmb / NSP, ktile = (gmb - bi * NSP) >> 6;
      const int m_l = T * 64 + (2 * kh2 + ti) * 16 + ccol;
      const int er0 = hh * 64 + (f * 4 + cq) * 8;
      short8 v; bf16* vp = (bf16*)&v;
#pragma unroll
      for (int j = 0; j < 8; ++j) vp[j] = ep[(er0 + j) * 132 + m_l];
      *(short8*)(k2_ws +
          (((size_t)(bi * 8 + h0 + hh) * 25 + ktile) * 512 + inner) * 8) = v;
    }
    // kt2_ws: per (bh,ktile) 512 chunks [kh][dt][quad][col]
#pragma unroll
    for (int it = 0; it < 8; ++it) {
      const int ci = it * 256 + tid;
      const int hh = ci >> 10, T = (ci >> 9) & 1, inner = ci & 511;
      const int ccol = inner & 15, cq = (inner >> 4) & 3;
      const int dt = (inner >> 6) & 3, kh2 = (inner >> 8) & 1;
      const int gmb = m0 + T * 64;
      const int bi = gmb / NSP, ktile = (gmb - bi * NSP) >> 6;
      const bf16* eprow =
          ep + (hh * 64 + dt * 16 + ccol) * 132 + T * 64 + kh2 * 32 + cq * 4;
      short8 v;
      ((bfx4*)&v)[0] = *(const bfx4*)(eprow);
      ((bfx4*)&v)[1] = *(const bfx4*)(eprow + 16);
      *(short8*)(kt2_ws +
          (((size_t)(bi * 8 + h0 + hh) * 25 + ktile) * 512 + inner) * 8) = v;
    }
  }
}

// ---------------------------------------------------------------------------
// attn: LDS-free K-loop, x2 manual unroll w/ named buffers, exp2 softmax.
// grid (25,32), 4 waves: qg=wave&1 (32 qcols), kh=wave>>1 (32 keys).
// ---------------------------------------------------------------------------
extern "C" __global__ __launch_bounds__(256)
void attn_kernel(const bf16* __restrict__ q_ws, const bf16* __restrict__ k2_ws,
                 const bf16* __restrict__ kt2_ws, float* __restrict__ out)
{
  __shared__ float red[2][64][36];

  const int qt = blockIdx.x, bh = blockIdx.y;
  const int b = bh >> 3, h = bh & 7;
  const int tid  = threadIdx.x;
  const int wave = tid >> 6;
  const int lane = tid & 63;
  const int col  = lane & 15;
  const int quad = lane >> 4;
  const int qg = wave & 1, kh = wave >> 1;

  // loop-invariant Q B-fragments
  short8 qb[2][2];
#pragma unroll
  for (int ct = 0; ct < 2; ++ct) {
    const bf16* qp =
        q_ws + ((size_t)bh * NSP + qt * 64 + (qg * 2 + ct) * 16 + col) * 64;
    qb[ct][0] = *(const short8*)(qp + quad * 8);
    qb[ct][1] = *(const short8*)(qp + 32 + quad * 8);
  }

  f32x4 oacc[4][2];
#pragma unroll
  for (int i = 0; i < 4; ++i)
#pragma unroll
    for (int j = 0; j < 2; ++j) oacc[i][j] = {0.f, 0.f, 0.f, 0.f};
  float l_part[2] = {0.f, 0.f};

  const bf16* k2b  = k2_ws  + (size_t)bh * 25 * 4096;
  const bf16* kt2b = kt2_ws + (size_t)bh * 25 * 4096;

  // Named double-buffer fragment sets (compile-time indices only!)
  short8 kfA[2][2], kfB[2][2];

#define LOADKF(DST, KT)                                                        \
  {                                                                            \
    const bf16* kc_ = k2b + (KT) * 4096;                                       \
    _Pragma("unroll")                                                          \
    for (int ti_ = 0; ti_ < 2; ++ti_)                                          \
      _Pragma("unroll")                                                        \
      for (int f_ = 0; f_ < 2; ++f_)                                           \
        DST[ti_][f_] = *(const short8*)(kc_ +                                  \
            (((kh * 2 + ti_) * 2 + f_) * 64 + lane) * 8);                      \
  }

#define BODY(KF, KT)                                                           \
  {                                                                            \
    const bf16* kc2_ = kt2b + (KT) * 4096;                                     \
    short8 ktf_[4];                                                            \
    _Pragma("unroll")                                                          \
    for (int dt_ = 0; dt_ < 4; ++dt_)                                          \
      ktf_[dt_] = *(const short8*)(kc2_ + ((kh * 4 + dt_) * 64 + lane) * 8);   \
    f32x4 s_[2][2];                                                            \
    _Pragma("unroll")                                                          \
    for (int ti_ = 0; ti_ < 2; ++ti_)                                          \
      _Pragma("unroll")                                                        \
      for (int ct_ = 0; ct_ < 2; ++ct_) {                                      \
        f32x4 t_ = {0.f, 0.f, 0.f, 0.f};                                      \
        t_ = mfma32(KF[ti_][0], qb[ct_][0], t_);                               \
        t_ = mfma32(KF[ti_][1], qb[ct_][1], t_);                               \
        s_[ti_][ct_] = t_;                                                     \
      }                                                                        \
    bfx4 p4_[2][2];                                                            \
    _Pragma("unroll")                                                          \
    for (int ti_ = 0; ti_ < 2; ++ti_)                                          \
      _Pragma("unroll")                                                        \
      for (int ct_ = 0; ct_ < 2; ++ct_) {                                      \
        _Pragma("unroll")                                                      \
        for (int r_ = 0; r_ < 4; ++r_) s_[ti_][ct_][r_] = exp2f(s_[ti_][ct_][r_]); \
        l_part[ct_] += s_[ti_][ct_][0] + s_[ti_][ct_][1] +                     \
                       s_[ti_][ct_][2] + s_[ti_][ct_][3];                      \
        bf16* pp_ = (bf16*)&p4_[ti_][ct_];                                     \
        _Pragma("unroll")                                                      \
        for (int r_ = 0; r_ < 4; ++r_) pp_[r_] = __float2bfloat16(s_[ti_][ct_][r_]); \
      }                                                                        \
    _Pragma("unroll")                                                          \
    for (int dt_ = 0; dt_ < 4; ++dt_) {                                        \
      bfx4 alo_ = __builtin_shufflevector(ktf_[dt_], ktf_[dt_], 0, 1, 2, 3);   \
      bfx4 ahi_ = __builtin_shufflevector(ktf_[dt_], ktf_[dt_], 4, 5, 6, 7);   \
      _Pragma("unroll")                                                        \
      for (int ct_ = 0; ct_ < 2; ++ct_) {                                      \
        oacc[dt_][ct_] = mfma_k16(alo_, p4_[0][ct_], oacc[dt_][ct_]);          \
        oacc[dt_][ct_] = mfma_k16(ahi_, p4_[1][ct_], oacc[dt_][ct_]);          \
      }                                                                        \
    }                                                                          \
  }

  LOADKF(kfA, 0)
  for (int kp = 0; kp < 12; ++kp) {
    const int kt0 = kp * 2;
    LOADKF(kfB, kt0 + 1)
    BODY(kfA, kt0)
    LOADKF(kfA, kt0 + 2)        // kt0+2 <= 24 always (kp <= 11)
    BODY(kfB, kt0 + 1)
  }
  BODY(kfA, 24)

  // reduce l over quads (this wave's 32 keys)
#pragma unroll
  for (int ct = 0; ct < 2; ++ct) {
    l_part[ct] += __shfl_xor(l_part[ct], 16, 64);
    l_part[ct] += __shfl_xor(l_part[ct], 32, 64);
  }

  // cross-wave (kh) reduce via LDS
  if (wave >= 2) {
    float* dst = &red[wave - 2][lane][0];
#pragma unroll
    for (int dt = 0; dt < 4; ++dt)
#pragma unroll
      for (int ct = 0; ct < 2; ++ct)
        *(f32x4*)(dst + (dt * 2 + ct) * 4) = oacc[dt][ct];
    dst[32] = l_part[0]; dst[33] = l_part[1];
  }
  __syncthreads();
  if (wave < 2) {
    const float* srcr = &red[wave][lane][0];
#pragma unroll
    for (int dt = 0; dt < 4; ++dt)
#pragma unroll
      for (int ct = 0; ct < 2; ++ct)
        oacc[dt][ct] += *(const f32x4*)(srcr + (dt * 2 + ct) * 4);
    const float inv0 = 1.f / (l_part[0] + srcr[32]);
    const float inv1 = 1.f / (l_part[1] + srcr[33]);
#pragma unroll
    for (int ct = 0; ct < 2; ++ct) {
      const float inv = ct ? inv1 : inv0;
      const int qrow = qt * 64 + (qg * 2 + ct) * 16 + col;
      float* ob = out + ((size_t)b * NSP + qrow) * CDIM + h * 64;
#pragma unroll
      for (int dt = 0; dt < 4; ++dt) {
        float4 v;
        v.x = oacc[dt][ct][0] * inv; v.y = oacc[dt][ct][1] * inv;
        v.z = oacc[dt][ct][2] * inv; v.w = oacc[dt][ct][3] * inv;
        *(float4*)(ob + dt * 16 + quad * 4) = v;
      }
    }
  }
}

extern "C" void kernel_launch(void* const* d_in, const int* in_sizes, int n_in,
                              void* d_out, int out_size, void* d_ws, size_t ws_size,
                              hipStream_t stream) {
  const float* x     = (const float*)d_in[0];
  const float* sin_t = (const float*)d_in[1];
  const float* cos_t = (const float*)d_in[2];
  const float* w_qkv = (const float*)d_in[3];
  const float* b_qkv = (const float*)d_in[4];
  float* out = (float*)d_out;

  const size_t QK = (size_t)32 * NSP * DH;
  bf16* q_ws   = (bf16*)d_ws;
  bf16* k2_ws  = q_ws + QK;
  bf16* kt2_ws = k2_ws + QK;
  bf16* x_bf   = kt2_ws + QK;
  bf16* w_bf   = x_bf + (size_t)6400 * CDIM;
  float* sinT  = (float*)(w_bf + (size_t)1024 * CDIM);
  float* cosT  = sinT + (size_t)DH * NSP;

  cvt_kernel<<<1906, 256, 0, stream>>>(x, w_qkv, sin_t, cos_t, x_bf, w_bf, sinT, cosT);

  dim3 gproj(50, 8);
  proj_kernel<<<gproj, 256, 0, stream>>>(x_bf, w_bf, b_qkv, sinT, cosT,
                                         q_ws, k2_ws, kt2_ws);

  dim3 gattn(25, 32);
  attn_kernel<<<gattn, 256, 0, stream>>>(q_ws, k2_ws, kt2_ws, out);
}